// Round 2
// baseline (304.783 us; speedup 1.0000x reference)
//
#include <hip/hip_runtime.h>

// Trilinear interpolation, grid (128,128,128,8) f32, 2M random points.
// Round 2: spatial binning (counting sort into 4^3-cell buckets) so the
// 8-corner gather becomes L2-local; only the 32B output rows scatter.

#define GS   128                 // grid spatial size
#define NBX  32                  // buckets per axis = GS/4
#define NBUCKET (NBX * NBX * NBX)   // 32768
#define SCAN_THREADS 1024
#define PER_THREAD (NBUCKET / SCAN_THREADS)  // 32

__device__ __forceinline__ void point_cell(
    float cx, float cy, float cz,
    float b0x, float b0y, float b0z,
    float sx, float sy, float sz,
    int& x0, int& y0, int& z0,
    float& wx, float& wy, float& wz)
{
    float nx = fminf(fmaxf((cx - b0x) / sx, 0.0f), 1.0f);
    float ny = fminf(fmaxf((cy - b0y) / sy, 0.0f), 1.0f);
    float nz = fminf(fmaxf((cz - b0z) / sz, 0.0f), 1.0f);
    float px = nx * (float)(GS - 1);
    float py = ny * (float)(GS - 1);
    float pz = nz * (float)(GS - 1);
    x0 = (int)px; y0 = (int)py; z0 = (int)pz;  // px>=0 -> trunc==floor
    wx = fminf(fmaxf(px - (float)x0, 0.0f), 1.0f);
    wy = fminf(fmaxf(py - (float)y0, 0.0f), 1.0f);
    wz = fminf(fmaxf(pz - (float)z0, 0.0f), 1.0f);
}

__device__ __forceinline__ int bucket_of(int x0, int y0, int z0) {
    return ((x0 >> 2) * NBX + (y0 >> 2)) * NBX + (z0 >> 2);
}

// ---------------- K1: histogram ----------------
__global__ __launch_bounds__(256) void k_hist(
    const float* __restrict__ coords,
    const float* __restrict__ bbox_min,
    const float* __restrict__ bbox_max,
    unsigned* __restrict__ hist, int n)
{
    int i = blockIdx.x * blockDim.x + threadIdx.x;
    if (i >= n) return;
    const float eps = 1e-6f;
    float b0x = bbox_min[0], b0y = bbox_min[1], b0z = bbox_min[2];
    float sx = fmaxf(bbox_max[0] - b0x, eps);
    float sy = fmaxf(bbox_max[1] - b0y, eps);
    float sz = fmaxf(bbox_max[2] - b0z, eps);
    int x0, y0, z0; float wx, wy, wz;
    point_cell(coords[3*i], coords[3*i+1], coords[3*i+2],
               b0x, b0y, b0z, sx, sy, sz, x0, y0, z0, wx, wy, wz);
    atomicAdd(&hist[bucket_of(x0, y0, z0)], 1u);
}

// ---------------- K2: exclusive scan over 32768 counters (1 block) --------
__global__ __launch_bounds__(SCAN_THREADS) void k_scan(
    const unsigned* __restrict__ hist,
    unsigned* __restrict__ offs)
{
    __shared__ unsigned s[SCAN_THREADS];
    int t = threadIdx.x;
    unsigned local[PER_THREAD];
    unsigned sum = 0;
#pragma unroll
    for (int j = 0; j < PER_THREAD; ++j) {
        local[j] = hist[t * PER_THREAD + j];
        sum += local[j];
    }
    s[t] = sum;
    __syncthreads();
    // Hillis-Steele inclusive scan of per-thread sums
    for (int d = 1; d < SCAN_THREADS; d <<= 1) {
        unsigned v = (t >= d) ? s[t - d] : 0u;
        __syncthreads();
        s[t] += v;
        __syncthreads();
    }
    unsigned excl = (t == 0) ? 0u : s[t - 1];
#pragma unroll
    for (int j = 0; j < PER_THREAD; ++j) {
        offs[t * PER_THREAD + j] = excl;
        excl += local[j];
    }
}

// ---------------- K3: scatter records into bucket order ----------------
__global__ __launch_bounds__(256) void k_scatter(
    const float* __restrict__ coords,
    const float* __restrict__ bbox_min,
    const float* __restrict__ bbox_max,
    unsigned* __restrict__ offs,
    float4* __restrict__ recs, int n)
{
    int i = blockIdx.x * blockDim.x + threadIdx.x;
    if (i >= n) return;
    const float eps = 1e-6f;
    float b0x = bbox_min[0], b0y = bbox_min[1], b0z = bbox_min[2];
    float sx = fmaxf(bbox_max[0] - b0x, eps);
    float sy = fmaxf(bbox_max[1] - b0y, eps);
    float sz = fmaxf(bbox_max[2] - b0z, eps);
    float cx = coords[3*i], cy = coords[3*i+1], cz = coords[3*i+2];
    int x0, y0, z0; float wx, wy, wz;
    point_cell(cx, cy, cz, b0x, b0y, b0z, sx, sy, sz, x0, y0, z0, wx, wy, wz);
    unsigned pos = atomicAdd(&offs[bucket_of(x0, y0, z0)], 1u);
    float4 r;
    r.x = cx; r.y = cy; r.z = cz; r.w = __uint_as_float((unsigned)i);
    recs[pos] = r;
}

// ---------------- K4: interpolate in sorted order ----------------
__global__ __launch_bounds__(256) void k_interp(
    const float4* __restrict__ recs,
    const float* __restrict__ grid,
    const float* __restrict__ bbox_min,
    const float* __restrict__ bbox_max,
    float* __restrict__ out, int n)
{
    int i = blockIdx.x * blockDim.x + threadIdx.x;
    if (i >= n) return;
    const float eps = 1e-6f;
    float b0x = bbox_min[0], b0y = bbox_min[1], b0z = bbox_min[2];
    float sx = fmaxf(bbox_max[0] - b0x, eps);
    float sy = fmaxf(bbox_max[1] - b0y, eps);
    float sz = fmaxf(bbox_max[2] - b0z, eps);

    float4 r = recs[i];
    unsigned orig = __float_as_uint(r.w);
    int x0, y0, z0; float wx, wy, wz;
    point_cell(r.x, r.y, r.z, b0x, b0y, b0z, sx, sy, sz, x0, y0, z0, wx, wy, wz);
    int x1 = min(x0 + 1, GS - 1);
    int y1 = min(y0 + 1, GS - 1);
    int z1 = min(z0 + 1, GS - 1);

    float ux = 1.0f - wx, uy = 1.0f - wy, uz = 1.0f - wz;
    float w000 = ux*uy*uz, w100 = wx*uy*uz, w010 = ux*wy*uz, w110 = wx*wy*uz;
    float w001 = ux*uy*wz, w101 = wx*uy*wz, w011 = ux*wy*wz, w111 = wx*wy*wz;

    const float4* g4 = (const float4*)grid;
    long long bx0 = (long long)x0 * GS;
    long long bx1 = (long long)x1 * GS;
    long long p000 = ((bx0 + y0) * GS + z0) * 2;
    long long p100 = ((bx1 + y0) * GS + z0) * 2;
    long long p010 = ((bx0 + y1) * GS + z0) * 2;
    long long p110 = ((bx1 + y1) * GS + z0) * 2;
    long long p001 = ((bx0 + y0) * GS + z1) * 2;
    long long p101 = ((bx1 + y0) * GS + z1) * 2;
    long long p011 = ((bx0 + y1) * GS + z1) * 2;
    long long p111 = ((bx1 + y1) * GS + z1) * 2;

    float4 a0 = g4[p000], a1 = g4[p000 + 1];
    float4 b0 = g4[p100], b1 = g4[p100 + 1];
    float4 c0 = g4[p010], c1 = g4[p010 + 1];
    float4 d0 = g4[p110], d1 = g4[p110 + 1];
    float4 e0 = g4[p001], e1 = g4[p001 + 1];
    float4 f0 = g4[p101], f1 = g4[p101 + 1];
    float4 h0 = g4[p011], h1 = g4[p011 + 1];
    float4 k0 = g4[p111], k1 = g4[p111 + 1];

    float4 o0, o1;
    o0.x = a0.x*w000 + b0.x*w100 + c0.x*w010 + d0.x*w110 + e0.x*w001 + f0.x*w101 + h0.x*w011 + k0.x*w111;
    o0.y = a0.y*w000 + b0.y*w100 + c0.y*w010 + d0.y*w110 + e0.y*w001 + f0.y*w101 + h0.y*w011 + k0.y*w111;
    o0.z = a0.z*w000 + b0.z*w100 + c0.z*w010 + d0.z*w110 + e0.z*w001 + f0.z*w101 + h0.z*w011 + k0.z*w111;
    o0.w = a0.w*w000 + b0.w*w100 + c0.w*w010 + d0.w*w110 + e0.w*w001 + f0.w*w101 + h0.w*w011 + k0.w*w111;
    o1.x = a1.x*w000 + b1.x*w100 + c1.x*w010 + d1.x*w110 + e1.x*w001 + f1.x*w101 + h1.x*w011 + k1.x*w111;
    o1.y = a1.y*w000 + b1.y*w100 + c1.y*w010 + d1.y*w110 + e1.y*w001 + f1.y*w101 + h1.y*w011 + k1.y*w111;
    o1.z = a1.z*w000 + b1.z*w100 + c1.z*w010 + d1.z*w110 + e1.z*w001 + f1.z*w101 + h1.z*w011 + k1.z*w111;
    o1.w = a1.w*w000 + b1.w*w100 + c1.w*w010 + d1.w*w110 + e1.w*w001 + f1.w*w101 + h1.w*w011 + k1.w*w111;

    float4* out4 = (float4*)out;
    out4[(long long)orig * 2 + 0] = o0;
    out4[(long long)orig * 2 + 1] = o1;
}

// ---------------- fallback: direct (round-1) kernel ----------------
__global__ __launch_bounds__(256) void trilerp_direct(
    const float* __restrict__ coords,
    const float* __restrict__ grid,
    const float* __restrict__ bbox_min,
    const float* __restrict__ bbox_max,
    float* __restrict__ out, int n)
{
    int i = blockIdx.x * blockDim.x + threadIdx.x;
    if (i >= n) return;
    const float eps = 1e-6f;
    float b0x = bbox_min[0], b0y = bbox_min[1], b0z = bbox_min[2];
    float sx = fmaxf(bbox_max[0] - b0x, eps);
    float sy = fmaxf(bbox_max[1] - b0y, eps);
    float sz = fmaxf(bbox_max[2] - b0z, eps);
    int x0, y0, z0; float wx, wy, wz;
    point_cell(coords[3*i], coords[3*i+1], coords[3*i+2],
               b0x, b0y, b0z, sx, sy, sz, x0, y0, z0, wx, wy, wz);
    int x1 = min(x0 + 1, GS - 1);
    int y1 = min(y0 + 1, GS - 1);
    int z1 = min(z0 + 1, GS - 1);
    float ux = 1.0f - wx, uy = 1.0f - wy, uz = 1.0f - wz;
    float w000 = ux*uy*uz, w100 = wx*uy*uz, w010 = ux*wy*uz, w110 = wx*wy*uz;
    float w001 = ux*uy*wz, w101 = wx*uy*wz, w011 = ux*wy*wz, w111 = wx*wy*wz;
    const float4* g4 = (const float4*)grid;
    long long bx0 = (long long)x0 * GS, bx1 = (long long)x1 * GS;
    long long p000 = ((bx0 + y0) * GS + z0) * 2, p100 = ((bx1 + y0) * GS + z0) * 2;
    long long p010 = ((bx0 + y1) * GS + z0) * 2, p110 = ((bx1 + y1) * GS + z0) * 2;
    long long p001 = ((bx0 + y0) * GS + z1) * 2, p101 = ((bx1 + y0) * GS + z1) * 2;
    long long p011 = ((bx0 + y1) * GS + z1) * 2, p111 = ((bx1 + y1) * GS + z1) * 2;
    float4 a0 = g4[p000], a1 = g4[p000+1], b0 = g4[p100], b1 = g4[p100+1];
    float4 c0 = g4[p010], c1 = g4[p010+1], d0 = g4[p110], d1 = g4[p110+1];
    float4 e0 = g4[p001], e1 = g4[p001+1], f0 = g4[p101], f1 = g4[p101+1];
    float4 h0 = g4[p011], h1 = g4[p011+1], k0 = g4[p111], k1 = g4[p111+1];
    float4 o0, o1;
    o0.x = a0.x*w000 + b0.x*w100 + c0.x*w010 + d0.x*w110 + e0.x*w001 + f0.x*w101 + h0.x*w011 + k0.x*w111;
    o0.y = a0.y*w000 + b0.y*w100 + c0.y*w010 + d0.y*w110 + e0.y*w001 + f0.y*w101 + h0.y*w011 + k0.y*w111;
    o0.z = a0.z*w000 + b0.z*w100 + c0.z*w010 + d0.z*w110 + e0.z*w001 + f0.z*w101 + h0.z*w011 + k0.z*w111;
    o0.w = a0.w*w000 + b0.w*w100 + c0.w*w010 + d0.w*w110 + e0.w*w001 + f0.w*w101 + h0.w*w011 + k0.w*w111;
    o1.x = a1.x*w000 + b1.x*w100 + c1.x*w010 + d1.x*w110 + e1.x*w001 + f1.x*w101 + h1.x*w011 + k1.x*w111;
    o1.y = a1.y*w000 + b1.y*w100 + c1.y*w010 + d1.y*w110 + e1.y*w001 + f1.y*w101 + h1.y*w011 + k1.y*w111;
    o1.z = a1.z*w000 + b1.z*w100 + c1.z*w010 + d1.z*w110 + e1.z*w001 + f1.z*w101 + h1.z*w011 + k1.z*w111;
    o1.w = a1.w*w000 + b1.w*w100 + c1.w*w010 + d1.w*w110 + e1.w*w001 + f1.w*w101 + h1.w*w011 + k1.w*w111;
    float4* out4 = (float4*)out;
    out4[(long long)i * 2 + 0] = o0;
    out4[(long long)i * 2 + 1] = o1;
}

extern "C" void kernel_launch(void* const* d_in, const int* in_sizes, int n_in,
                              void* d_out, int out_size, void* d_ws, size_t ws_size,
                              hipStream_t stream) {
    const float* coords   = (const float*)d_in[0];
    const float* grid     = (const float*)d_in[1];
    const float* bbox_min = (const float*)d_in[2];
    const float* bbox_max = (const float*)d_in[3];
    float* out = (float*)d_out;

    int n = in_sizes[0] / 3;
    int block = 256;
    int nblocks = (n + block - 1) / block;

    size_t hist_bytes = (size_t)NBUCKET * 4;
    size_t offs_off   = hist_bytes;                  // 128 KB
    size_t recs_off   = hist_bytes * 2;              // 256 KB (16B aligned)
    size_t needed     = recs_off + (size_t)n * 16;

    if (ws_size < needed) {
        trilerp_direct<<<nblocks, block, 0, stream>>>(coords, grid, bbox_min, bbox_max, out, n);
        return;
    }

    unsigned* hist = (unsigned*)d_ws;
    unsigned* offs = (unsigned*)((char*)d_ws + offs_off);
    float4*   recs = (float4*)((char*)d_ws + recs_off);

    hipMemsetAsync(hist, 0, hist_bytes, stream);
    k_hist<<<nblocks, block, 0, stream>>>(coords, bbox_min, bbox_max, hist, n);
    k_scan<<<1, SCAN_THREADS, 0, stream>>>(hist, offs);
    k_scatter<<<nblocks, block, 0, stream>>>(coords, bbox_min, bbox_max, offs, recs, n);
    k_interp<<<nblocks, block, 0, stream>>>(recs, grid, bbox_min, bbox_max, out, n);
}